// Round 1
// baseline (171.497 us; speedup 1.0000x reference)
//
#include <hip/hip_runtime.h>
#include <math.h>

#define EPSILON 1e-6f
#define COS_EPS 1e-8f
#define NN 2048
#define FF 128
#define BLK 512   // 8 waves

__launch_bounds__(BLK, 2)
__global__ void ntm_head_kernel(const float* __restrict__ m,
                                const float* __restrict__ kk,
                                const float* __restrict__ beta_,
                                const float* __restrict__ g_,
                                const float* __restrict__ s_,
                                const float* __restrict__ r_,
                                const float* __restrict__ wp,
                                float* __restrict__ out) {
  const int b   = blockIdx.x;
  const int tid = threadIdx.x;
  const int wv  = tid >> 6;     // wave id 0..7
  const int lane = tid & 63;

  __shared__ float simbuf[NN];  // beta*sim, then exp()
  __shared__ float warr[NN];    // interpolated weights
  __shared__ float red[8];
  __shared__ float bc;

  // per-batch scalars (L1-cached scalarizable loads)
  const float beta = beta_[b];
  const float gg   = g_[b];
  const float s0 = s_[b * 3 + 0], s1 = s_[b * 3 + 1], s2 = s_[b * 3 + 2];
  const float rr = r_[b];

  // key fragment: lane holds k[2*lane], k[2*lane+1]  (F=128 = 64 lanes * 2)
  float2 kv = *reinterpret_cast<const float2*>(kk + (size_t)b * FF + 2 * lane);
  const float kex = kv.x + EPSILON;
  const float key = kv.y + EPSILON;
  float ksq = kex * kex + key * key;
  #pragma unroll
  for (int off = 1; off < 64; off <<= 1) ksq += __shfl_xor(ksq, off);
  const float knorm = sqrtf(ksq);

  const float* mb = m + (size_t)b * NN * FF;

  // ---- content addressing: one row per wave, 4 rows in flight ----
  float amax = -INFINITY;
  for (int rw = 0; rw < NN / 8; rw += 4) {
    float2 mv[4];
    #pragma unroll
    for (int u = 0; u < 4; ++u) {
      int n = (rw + u) * 8 + wv;
      mv[u] = *reinterpret_cast<const float2*>(mb + (size_t)n * FF + 2 * lane);
    }
    #pragma unroll
    for (int u = 0; u < 4; ++u) {
      int n = (rw + u) * 8 + wv;
      float mex = mv[u].x + EPSILON;
      float mey = mv[u].y + EPSILON;
      float dp = mex * kex + mey * key;
      float sq = mex * mex + mey * mey;
      #pragma unroll
      for (int off = 1; off < 64; off <<= 1) {
        dp += __shfl_xor(dp, off);
        sq += __shfl_xor(sq, off);
      }
      float a = beta * (dp / fmaxf(sqrtf(sq) * knorm, COS_EPS));
      if (lane == 0) simbuf[n] = a;
      amax = fmaxf(amax, a);
    }
  }

  // ---- block max over beta*sim ----
  __syncthreads();
  if (lane == 0) red[wv] = amax;
  __syncthreads();
  if (tid == 0) {
    float v = red[0];
    #pragma unroll
    for (int i = 1; i < 8; ++i) v = fmaxf(v, red[i]);
    bc = v;
  }
  __syncthreads();
  const float amax_all = bc;

  // ---- softmax exp + sum ----
  float lsum = 0.f;
  #pragma unroll
  for (int i = 0; i < NN / BLK; ++i) {
    int n = tid + i * BLK;
    float e = expf(simbuf[n] - amax_all);
    simbuf[n] = e;
    lsum += e;
  }
  #pragma unroll
  for (int off = 1; off < 64; off <<= 1) lsum += __shfl_xor(lsum, off);
  __syncthreads();              // protect red[] reuse
  if (lane == 0) red[wv] = lsum;
  __syncthreads();
  if (tid == 0) {
    float v = 0.f;
    #pragma unroll
    for (int i = 0; i < 8; ++i) v += red[i];
    bc = v;
  }
  __syncthreads();
  const float inv_softmax = 1.0f / bc;   // jax.nn.softmax has no epsilon
  const float om_g = 1.0f - gg;

  // ---- interpolation: w = softmax + (1-g)*w_prev ----
  #pragma unroll
  for (int i = 0; i < NN / BLK; ++i) {
    int n = tid + i * BLK;
    warr[n] = simbuf[n] * inv_softmax + om_g * wp[(size_t)b * NN + n];
  }
  __syncthreads();

  // ---- circular shift (3-tap) + sharpen ----
  float wrv[NN / BLK];
  float lsum2 = 0.f;
  #pragma unroll
  for (int i = 0; i < NN / BLK; ++i) {
    int n = tid + i * BLK;
    float prev = warr[(n + NN - 1) & (NN - 1)];
    float cur  = warr[n];
    float nxt  = warr[(n + 1) & (NN - 1)];
    float sh = s0 * prev + s1 * cur + s2 * nxt;   // strictly > 0
    float p = powf(sh, rr);
    wrv[i] = p;
    lsum2 += p;
  }
  #pragma unroll
  for (int off = 1; off < 64; off <<= 1) lsum2 += __shfl_xor(lsum2, off);
  __syncthreads();              // protect red[] reuse
  if (lane == 0) red[wv] = lsum2;
  __syncthreads();
  if (tid == 0) {
    float v = 0.f;
    #pragma unroll
    for (int i = 0; i < 8; ++i) v += red[i];
    bc = v;
  }
  __syncthreads();
  const float inv_sharp = 1.0f / (bc + EPSILON);

  #pragma unroll
  for (int i = 0; i < NN / BLK; ++i) {
    int n = tid + i * BLK;
    out[(size_t)b * NN + n] = wrv[i] * inv_sharp;
  }
}

extern "C" void kernel_launch(void* const* d_in, const int* in_sizes, int n_in,
                              void* d_out, int out_size, void* d_ws, size_t ws_size,
                              hipStream_t stream) {
  const float* m  = (const float*)d_in[0];
  const float* k  = (const float*)d_in[1];
  const float* b  = (const float*)d_in[2];
  const float* g  = (const float*)d_in[3];
  const float* s  = (const float*)d_in[4];
  const float* r  = (const float*)d_in[5];
  const float* wp = (const float*)d_in[6];
  float* out = (float*)d_out;

  ntm_head_kernel<<<dim3(512), dim3(BLK), 0, stream>>>(m, k, b, g, s, r, wp, out);
}

// Round 2
// 104.765 us; speedup vs baseline: 1.6370x; 1.6370x over previous
//
#include <hip/hip_runtime.h>
#include <math.h>

#define EPSILON 1e-6f
#define COS_EPS 1e-8f
#define NN 2048
#define FF 128
#define BLK 512   // 8 waves

__launch_bounds__(BLK, 2)
__global__ void ntm_head_kernel(const float* __restrict__ m,
                                const float* __restrict__ kk,
                                const float* __restrict__ beta_,
                                const float* __restrict__ g_,
                                const float* __restrict__ s_,
                                const float* __restrict__ r_,
                                const float* __restrict__ wp,
                                float* __restrict__ out) {
  const int b    = blockIdx.x;
  const int tid  = threadIdx.x;
  const int wv   = tid >> 6;      // wave id 0..7
  const int lane = tid & 63;
  const int h    = lane >> 5;     // half-wave id 0/1
  const int l32  = lane & 31;

  __shared__ float simbuf[NN];  // beta*sim, then exp()
  __shared__ float warr[NN];    // interpolated weights
  __shared__ float red[8];
  __shared__ float bc;

  // per-batch scalars
  const float beta = beta_[b];
  const float gg   = g_[b];
  const float s0 = s_[b * 3 + 0], s1 = s_[b * 3 + 1], s2 = s_[b * 3 + 2];
  const float rr = r_[b];

  // key fragment: lane holds k[4*l32 .. 4*l32+3]  (F=128 = 32 lanes * 4)
  float4 kv = *reinterpret_cast<const float4*>(kk + (size_t)b * FF + 4 * l32);
  const float ke0 = kv.x + EPSILON, ke1 = kv.y + EPSILON;
  const float ke2 = kv.z + EPSILON, ke3 = kv.w + EPSILON;
  float ksq = ke0 * ke0 + ke1 * ke1 + ke2 * ke2 + ke3 * ke3;
  #pragma unroll
  for (int off = 1; off < 32; off <<= 1) ksq += __shfl_xor(ksq, off);
  const float knorm = sqrtf(ksq);

  const float* mb = m + (size_t)b * NN * FF;

  // ---- content addressing: one row per half-wave, 8 rows in flight/wave ----
  float amax = -INFINITY;
  for (int it = 0; it < NN / 16; it += 4) {
    float4 mv[4];
    #pragma unroll
    for (int u = 0; u < 4; ++u) {
      int n = (it + u) * 16 + wv * 2 + h;
      mv[u] = *reinterpret_cast<const float4*>(mb + (size_t)n * FF + 4 * l32);
    }
    #pragma unroll
    for (int u = 0; u < 4; ++u) {
      int n = (it + u) * 16 + wv * 2 + h;
      float m0 = mv[u].x + EPSILON, m1 = mv[u].y + EPSILON;
      float m2 = mv[u].z + EPSILON, m3 = mv[u].w + EPSILON;
      float dp = m0 * ke0 + m1 * ke1 + m2 * ke2 + m3 * ke3;
      float sq = m0 * m0 + m1 * m1 + m2 * m2 + m3 * m3;
      #pragma unroll
      for (int off = 1; off < 32; off <<= 1) {   // 5 steps, serves both halves
        dp += __shfl_xor(dp, off);
        sq += __shfl_xor(sq, off);
      }
      float a = beta * (dp / fmaxf(sqrtf(sq) * knorm, COS_EPS));
      if (l32 == 0) simbuf[n] = a;
      amax = fmaxf(amax, a);
    }
  }
  amax = fmaxf(amax, __shfl_xor(amax, 32));  // merge the two halves' maxima

  // ---- block max over beta*sim ----
  __syncthreads();
  if (lane == 0) red[wv] = amax;
  __syncthreads();
  if (tid == 0) {
    float v = red[0];
    #pragma unroll
    for (int i = 1; i < 8; ++i) v = fmaxf(v, red[i]);
    bc = v;
  }
  __syncthreads();
  const float amax_all = bc;

  // ---- softmax exp + sum ----
  float lsum = 0.f;
  #pragma unroll
  for (int i = 0; i < NN / BLK; ++i) {
    int n = tid + i * BLK;
    float e = expf(simbuf[n] - amax_all);
    simbuf[n] = e;
    lsum += e;
  }
  #pragma unroll
  for (int off = 1; off < 64; off <<= 1) lsum += __shfl_xor(lsum, off);
  __syncthreads();              // protect red[] reuse
  if (lane == 0) red[wv] = lsum;
  __syncthreads();
  if (tid == 0) {
    float v = 0.f;
    #pragma unroll
    for (int i = 0; i < 8; ++i) v += red[i];
    bc = v;
  }
  __syncthreads();
  const float inv_softmax = 1.0f / bc;   // jax.nn.softmax has no epsilon
  const float om_g = 1.0f - gg;

  // ---- interpolation: w = softmax + (1-g)*w_prev ----
  #pragma unroll
  for (int i = 0; i < NN / BLK; ++i) {
    int n = tid + i * BLK;
    warr[n] = simbuf[n] * inv_softmax + om_g * wp[(size_t)b * NN + n];
  }
  __syncthreads();

  // ---- circular shift (3-tap) + sharpen ----
  float wrv[NN / BLK];
  float lsum2 = 0.f;
  #pragma unroll
  for (int i = 0; i < NN / BLK; ++i) {
    int n = tid + i * BLK;
    float prev = warr[(n + NN - 1) & (NN - 1)];
    float cur  = warr[n];
    float nxt  = warr[(n + 1) & (NN - 1)];
    float sh = s0 * prev + s1 * cur + s2 * nxt;   // strictly > 0
    float p = powf(sh, rr);
    wrv[i] = p;
    lsum2 += p;
  }
  #pragma unroll
  for (int off = 1; off < 64; off <<= 1) lsum2 += __shfl_xor(lsum2, off);
  __syncthreads();              // protect red[] reuse
  if (lane == 0) red[wv] = lsum2;
  __syncthreads();
  if (tid == 0) {
    float v = 0.f;
    #pragma unroll
    for (int i = 0; i < 8; ++i) v += red[i];
    bc = v;
  }
  __syncthreads();
  const float inv_sharp = 1.0f / (bc + EPSILON);

  #pragma unroll
  for (int i = 0; i < NN / BLK; ++i) {
    int n = tid + i * BLK;
    out[(size_t)b * NN + n] = wrv[i] * inv_sharp;
  }
}

extern "C" void kernel_launch(void* const* d_in, const int* in_sizes, int n_in,
                              void* d_out, int out_size, void* d_ws, size_t ws_size,
                              hipStream_t stream) {
  const float* m  = (const float*)d_in[0];
  const float* k  = (const float*)d_in[1];
  const float* b  = (const float*)d_in[2];
  const float* g  = (const float*)d_in[3];
  const float* s  = (const float*)d_in[4];
  const float* r  = (const float*)d_in[5];
  const float* wp = (const float*)d_in[6];
  float* out = (float*)d_out;

  ntm_head_kernel<<<dim3(512), dim3(BLK), 0, stream>>>(m, k, b, g, s, r, wp, out);
}

// Round 3
// 103.634 us; speedup vs baseline: 1.6548x; 1.0109x over previous
//
#include <hip/hip_runtime.h>
#include <math.h>

#define EPSILON 1e-6f
#define COS_EPS 1e-8f
#define NN 2048
#define FF 128
#define BLK 512     // 8 waves
#define UNROLL 8    // rows in flight per wave = 2*UNROLL

__launch_bounds__(BLK, 2)
__global__ void ntm_head_kernel(const float* __restrict__ m,
                                const float* __restrict__ kk,
                                const float* __restrict__ beta_,
                                const float* __restrict__ g_,
                                const float* __restrict__ s_,
                                const float* __restrict__ r_,
                                const float* __restrict__ wp,
                                float* __restrict__ out) {
  const int b    = blockIdx.x;
  const int tid  = threadIdx.x;
  const int wv   = tid >> 6;      // wave id 0..7
  const int lane = tid & 63;
  const int h    = lane >> 5;     // half-wave id 0/1
  const int l32  = lane & 31;

  __shared__ float simbuf[NN];    // exp(beta*sim)
  __shared__ float warr[NN];      // interpolated weights
  __shared__ float red_s[8];      // per-wave softmax partial sums
  __shared__ float red_p[8];      // per-wave sharpen partial sums

  // prefetch w_prev into registers: latency hides under the content stream
  float wprv[NN / BLK];
  #pragma unroll
  for (int i = 0; i < NN / BLK; ++i)
    wprv[i] = wp[(size_t)b * NN + tid + i * BLK];

  // per-batch scalars
  const float beta = beta_[b];
  const float gg   = g_[b];
  const float s0 = s_[b * 3 + 0], s1 = s_[b * 3 + 1], s2 = s_[b * 3 + 2];
  const float rr = r_[b];

  // key fragment: lane holds k[4*l32 .. 4*l32+3]  (F=128 = 32 lanes * 4)
  float4 kv = *reinterpret_cast<const float4*>(kk + (size_t)b * FF + 4 * l32);
  const float ke0 = kv.x + EPSILON, ke1 = kv.y + EPSILON;
  const float ke2 = kv.z + EPSILON, ke3 = kv.w + EPSILON;
  float ksq = ke0 * ke0 + ke1 * ke1 + ke2 * ke2 + ke3 * ke3;
  #pragma unroll
  for (int off = 1; off < 32; off <<= 1) ksq += __shfl_xor(ksq, off);
  const float inv_knorm = __builtin_amdgcn_rsqf(ksq);   // 1/||k+eps||

  const float* mb = m + (size_t)b * NN * FF;

  // ---- content addressing + fused exp + fused denominator accumulation ----
  // beta*sim in [-5,5] (|cos|<=1, b<5) so exp() is overflow-safe without
  // max subtraction (mathematically identical to softmax).
  float lsum = 0.f;   // each lane accumulates its half's row-exp sum (identical within half)
  for (int it = 0; it < NN / 16; it += UNROLL) {
    float4 mv[UNROLL];
    #pragma unroll
    for (int u = 0; u < UNROLL; ++u) {
      int n = (it + u) * 16 + wv * 2 + h;
      mv[u] = *reinterpret_cast<const float4*>(mb + (size_t)n * FF + 4 * l32);
    }
    #pragma unroll
    for (int u = 0; u < UNROLL; ++u) {
      int n = (it + u) * 16 + wv * 2 + h;
      float m0 = mv[u].x + EPSILON, m1 = mv[u].y + EPSILON;
      float m2 = mv[u].z + EPSILON, m3 = mv[u].w + EPSILON;
      float dp = m0 * ke0 + m1 * ke1 + m2 * ke2 + m3 * ke3;
      float sq = m0 * m0 + m1 * m1 + m2 * m2 + m3 * m3;
      #pragma unroll
      for (int off = 1; off < 32; off <<= 1) {   // 5 steps, serves both halves
        dp += __shfl_xor(dp, off);
        sq += __shfl_xor(sq, off);
      }
      // a = beta * dp / (sqrt(sq)*knorm); rsq+rcp: ~1ulp, tolerance headroom 340x
      float a = beta * dp * __builtin_amdgcn_rsqf(sq) * inv_knorm;
      float e = __expf(a);
      if (l32 == 0) simbuf[n] = e;
      lsum += e;
    }
  }
  lsum += __shfl_xor(lsum, 32);      // merge halves -> wave total
  if (lane == 0) red_s[wv] = lsum;
  __syncthreads();                   // #1: simbuf + red_s ready

  // block softmax denominator via broadcast reads (no second barrier)
  float ssum = 0.f;
  #pragma unroll
  for (int i = 0; i < 8; ++i) ssum += red_s[i];
  const float inv_softmax = 1.0f / ssum;   // jax softmax: no epsilon
  const float om_g = 1.0f - gg;

  // ---- interpolation: w = softmax + (1-g)*w_prev ----
  #pragma unroll
  for (int i = 0; i < NN / BLK; ++i) {
    int n = tid + i * BLK;
    warr[n] = simbuf[n] * inv_softmax + om_g * wprv[i];
  }
  __syncthreads();                   // #2: warr ready

  // ---- circular shift (3-tap) + sharpen ----
  float wrv[NN / BLK];
  float lsum2 = 0.f;
  #pragma unroll
  for (int i = 0; i < NN / BLK; ++i) {
    int n = tid + i * BLK;
    float prev = warr[(n + NN - 1) & (NN - 1)];
    float cur  = warr[n];
    float nxt  = warr[(n + 1) & (NN - 1)];
    float sh = s0 * prev + s1 * cur + s2 * nxt;   // strictly > 0
    float p = __expf(rr * __logf(sh));            // sh^r
    wrv[i] = p;
    lsum2 += p;
  }
  #pragma unroll
  for (int off = 1; off < 64; off <<= 1) lsum2 += __shfl_xor(lsum2, off);
  if (lane == 0) red_p[wv] = lsum2;
  __syncthreads();                   // #3: red_p ready

  float psum = 0.f;
  #pragma unroll
  for (int i = 0; i < 8; ++i) psum += red_p[i];
  const float inv_sharp = 1.0f / (psum + EPSILON);

  #pragma unroll
  for (int i = 0; i < NN / BLK; ++i) {
    int n = tid + i * BLK;
    out[(size_t)b * NN + n] = wrv[i] * inv_sharp;
  }
}

extern "C" void kernel_launch(void* const* d_in, const int* in_sizes, int n_in,
                              void* d_out, int out_size, void* d_ws, size_t ws_size,
                              hipStream_t stream) {
  const float* m  = (const float*)d_in[0];
  const float* k  = (const float*)d_in[1];
  const float* b  = (const float*)d_in[2];
  const float* g  = (const float*)d_in[3];
  const float* s  = (const float*)d_in[4];
  const float* r  = (const float*)d_in[5];
  const float* wp = (const float*)d_in[6];
  float* out = (float*)d_out;

  ntm_head_kernel<<<dim3(512), dim3(BLK), 0, stream>>>(m, k, b, g, s, r, wp, out);
}

// Round 5
// 95.613 us; speedup vs baseline: 1.7937x; 1.0839x over previous
//
#include <hip/hip_runtime.h>
#include <math.h>

#define EPSILON 1e-6f
#define COS_EPS 1e-8f
#define NN 2048
#define FF 128
#define BLK 512     // 8 waves
#define UNROLL 8    // rows in flight per wave = 2*UNROLL

typedef float floatx4 __attribute__((ext_vector_type(4)));  // native vec for nontemporal builtin

__launch_bounds__(BLK, 2)
__global__ void ntm_head_kernel(const float* __restrict__ m,
                                const float* __restrict__ kk,
                                const float* __restrict__ beta_,
                                const float* __restrict__ g_,
                                const float* __restrict__ s_,
                                const float* __restrict__ r_,
                                const float* __restrict__ wp,
                                float* __restrict__ out) {
  const int b    = blockIdx.x;
  const int tid  = threadIdx.x;
  const int wv   = tid >> 6;      // wave id 0..7
  const int lane = tid & 63;
  const int h    = lane >> 5;     // half-wave id 0/1
  const int l32  = lane & 31;

  __shared__ float simbuf[NN];    // exp(beta*sim)
  __shared__ float warr[NN];      // interpolated weights
  __shared__ float red_s[8];      // per-wave softmax partial sums
  __shared__ float red_p[8];      // per-wave sharpen partial sums

  // prefetch w_prev into registers (one dwordx4): hides under content stream
  float4 wprv4 = *reinterpret_cast<const float4*>(wp + (size_t)b * NN + 4 * tid);

  // per-batch scalars
  const float beta = beta_[b];
  const float gg   = g_[b];
  const float s0 = s_[b * 3 + 0], s1 = s_[b * 3 + 1], s2 = s_[b * 3 + 2];
  const float rr = r_[b];

  // key fragment: lane holds k[4*l32 .. 4*l32+3]  (F=128 = 32 lanes * 4)
  float4 kv = *reinterpret_cast<const float4*>(kk + (size_t)b * FF + 4 * l32);
  const float ke0 = kv.x + EPSILON, ke1 = kv.y + EPSILON;
  const float ke2 = kv.z + EPSILON, ke3 = kv.w + EPSILON;
  float ksq = ke0 * ke0 + ke1 * ke1 + ke2 * ke2 + ke3 * ke3;
  #pragma unroll
  for (int off = 1; off < 32; off <<= 1) ksq += __shfl_xor(ksq, off);
  const float inv_knorm = __builtin_amdgcn_rsqf(ksq);   // 1/||k+eps||

  const float* mb = m + (size_t)b * NN * FF;

  // ---- content addressing + fused exp + fused denominator accumulation ----
  // beta*sim in [-5,5] (|cos|<=1, b<5) so exp() is overflow-safe without
  // max subtraction (mathematically identical to softmax).
  float lsum = 0.f;
  for (int it = 0; it < NN / 16; it += UNROLL) {
    floatx4 mv[UNROLL];
    #pragma unroll
    for (int u = 0; u < UNROLL; ++u) {
      int n = (it + u) * 16 + wv * 2 + h;
      // non-temporal: m has zero reuse — skip cache allocation on the stream
      mv[u] = __builtin_nontemporal_load(
          reinterpret_cast<const floatx4*>(mb + (size_t)n * FF + 4 * l32));
    }
    #pragma unroll
    for (int u = 0; u < UNROLL; ++u) {
      int n = (it + u) * 16 + wv * 2 + h;
      float m0 = mv[u].x + EPSILON, m1 = mv[u].y + EPSILON;
      float m2 = mv[u].z + EPSILON, m3 = mv[u].w + EPSILON;
      float dp = m0 * ke0 + m1 * ke1 + m2 * ke2 + m3 * ke3;
      float sq = m0 * m0 + m1 * m1 + m2 * m2 + m3 * m3;
      #pragma unroll
      for (int off = 1; off < 32; off <<= 1) {   // 5 steps, serves both halves
        dp += __shfl_xor(dp, off);
        sq += __shfl_xor(sq, off);
      }
      float a = beta * dp * __builtin_amdgcn_rsqf(sq) * inv_knorm;
      float e = __expf(a);
      if (l32 == 0) simbuf[n] = e;
      lsum += e;
    }
  }
  lsum += __shfl_xor(lsum, 32);      // merge halves -> wave total
  if (lane == 0) red_s[wv] = lsum;
  __syncthreads();                   // #1: simbuf + red_s ready

  float ssum = 0.f;
  #pragma unroll
  for (int i = 0; i < 8; ++i) ssum += red_s[i];
  const float inv_softmax = 1.0f / ssum;   // jax softmax: no epsilon
  const float om_g = 1.0f - gg;

  // ---- interpolation: w = softmax + (1-g)*w_prev ----
  {
    int n0 = 4 * tid;
    warr[n0 + 0] = simbuf[n0 + 0] * inv_softmax + om_g * wprv4.x;
    warr[n0 + 1] = simbuf[n0 + 1] * inv_softmax + om_g * wprv4.y;
    warr[n0 + 2] = simbuf[n0 + 2] * inv_softmax + om_g * wprv4.z;
    warr[n0 + 3] = simbuf[n0 + 3] * inv_softmax + om_g * wprv4.w;
  }
  __syncthreads();                   // #2: warr ready

  // ---- circular shift (3-tap) + sharpen ----
  float wrv[NN / BLK];
  float lsum2 = 0.f;
  #pragma unroll
  for (int i = 0; i < NN / BLK; ++i) {
    int n = tid + i * BLK;
    float prev = warr[(n + NN - 1) & (NN - 1)];
    float cur  = warr[n];
    float nxt  = warr[(n + 1) & (NN - 1)];
    float sh = s0 * prev + s1 * cur + s2 * nxt;   // strictly > 0
    float p = __expf(rr * __logf(sh));            // sh^r
    wrv[i] = p;
    lsum2 += p;
  }
  #pragma unroll
  for (int off = 1; off < 64; off <<= 1) lsum2 += __shfl_xor(lsum2, off);
  if (lane == 0) red_p[wv] = lsum2;
  __syncthreads();                   // #3: red_p ready

  float psum = 0.f;
  #pragma unroll
  for (int i = 0; i < 8; ++i) psum += red_p[i];
  const float inv_sharp = 1.0f / (psum + EPSILON);

  #pragma unroll
  for (int i = 0; i < NN / BLK; ++i) {
    int n = tid + i * BLK;
    out[(size_t)b * NN + n] = wrv[i] * inv_sharp;
  }
}

extern "C" void kernel_launch(void* const* d_in, const int* in_sizes, int n_in,
                              void* d_out, int out_size, void* d_ws, size_t ws_size,
                              hipStream_t stream) {
  const float* m  = (const float*)d_in[0];
  const float* k  = (const float*)d_in[1];
  const float* b  = (const float*)d_in[2];
  const float* g  = (const float*)d_in[3];
  const float* s  = (const float*)d_in[4];
  const float* r  = (const float*)d_in[5];
  const float* wp = (const float*)d_in[6];
  float* out = (float*)d_out;

  ntm_head_kernel<<<dim3(512), dim3(BLK), 0, stream>>>(m, k, b, g, s, r, wp, out);
}